// Round 8
// baseline (1011.541 us; speedup 1.0000x reference)
//
#include <hip/hip_runtime.h>
#include <hip/hip_bf16.h>

// ---------------------------------------------------------------------------
// 3-axis window attention, MI355X gfx950.  Round 6 (fixed build): VALU diet.
//  - All bf16 conversions via HW v_cvt_pk_bf16_f32 (__float22bfloat162_rn /
//    __float2bfloat16) instead of 4-op manual RNE (~1000 VALU/wave saved).
//  - Q bias folded into fmaf; s_setprio(1) around MFMA clusters (T5).
//  - Structure unchanged from R5: single fused dispatch, S^T in-register
//    softmax, 48KB LDS aliased, 6 barriers, atomicAdd epilogue.
// ---------------------------------------------------------------------------

typedef __attribute__((ext_vector_type(8))) short short8v;   // 8 x bf16 frag
typedef __attribute__((ext_vector_type(2))) unsigned uint2v; // 2x2 bf16 packed
typedef __attribute__((ext_vector_type(4))) float floatx4;

#define MFMA16(a, b, c) __builtin_amdgcn_mfma_f32_16x16x32_bf16((a), (b), (c), 0, 0, 0)

#define SWZ8(row, b)  ((b) ^ (((row) & 7) << 4))
#define SWZ16(row, b) ((b) ^ (((row) & 15) << 4))

__device__ __forceinline__ unsigned pk2(float a, float b) {  // v_cvt_pk_bf16_f32
  __hip_bfloat162 h = __float22bfloat162_rn(make_float2(a, b));
  unsigned u;
  __builtin_memcpy(&u, &h, 4);
  return u;
}
__device__ __forceinline__ void st16(void* p, float v) {     // scalar bf16 store
  *(__hip_bfloat16*)p = __float2bfloat16(v);
}

// ---- LDS regions (bytes), total 48 KB -> 3 blocks/CU ----
#define RA 0        // [64][256B] XS  ->  [128][128B] VT  ->  [64][256B] O
#define RB 16384    // [64][256B] Q   ->  P[h0],P[h1]  ([64][128B] each)
#define RC 32768    // [64][256B] K   ->  P[h2],P[h3]
#define LDS_BYTES 49152

__global__ void prep_weights(const float* __restrict__ q0, const float* __restrict__ q1,
                             const float* __restrict__ q2, const float* __restrict__ p0,
                             const float* __restrict__ p1, const float* __restrict__ p2,
                             short* __restrict__ ws) {
  // ws: qkvT[3][384][128] bf16 then projT[3][128][128] bf16 ([out_col][k])
  int idx = blockIdx.x * 256 + threadIdx.x;
  if (idx < 3 * 49152) {
    int b = idx / 49152, r = idx % 49152;
    int n = r >> 7, k = r & 127;
    const float* s = (b == 0) ? q0 : (b == 1) ? q1 : q2;
    short v; __hip_bfloat16 h = __float2bfloat16(s[k * 384 + n]);
    __builtin_memcpy(&v, &h, 2);
    ws[idx] = v;
  } else if (idx < 3 * 49152 + 3 * 16384) {
    int j = idx - 3 * 49152;
    int b = j / 16384, r = j % 16384;
    int n = r >> 7, k = r & 127;
    const float* s = (b == 0) ? p0 : (b == 1) ? p1 : p2;
    short v; __hip_bfloat16 h = __float2bfloat16(s[k * 128 + n]);
    __builtin_memcpy(&v, &h, 2);
    ws[idx] = v;
  }
}

__global__ __launch_bounds__(512, 6)
void wattn_all(const float* __restrict__ x, const short* __restrict__ wsT,
               const float* __restrict__ bq0, const float* __restrict__ bq1,
               const float* __restrict__ bq2, const float* __restrict__ bp0,
               const float* __restrict__ bp1, const float* __restrict__ bp2,
               float* __restrict__ out, int nb0, int nb1) {
  __shared__ alignas(256) char smem[LDS_BYTES];
  const int tid = threadIdx.x;
  const int w = tid >> 6;            // wave 0..7
  const int l = tid & 63;
  const int l15 = l & 15;
  const int l4 = l >> 4;             // 0..3
  const float SCALE = 0.17677669529663687f;  // 32^-0.5
  const floatx4 ZERO4 = {0.f, 0.f, 0.f, 0.f};

  // ---- branch resolve (all wave-uniform) ----
  const int bid = blockIdx.x;
  const int br = (bid >= nb0) + (bid >= nb0 + nb1);
  const int lbid = bid - (br == 0 ? 0 : (br == 1 ? nb0 : nb0 + nb1));
  const int NTOK = (br == 0) ? 49 : 56;
  const int S1 = (br == 0) ? 56 : 3136;   // token stride for t/7
  const int S2 = (br == 1) ? 56 : 1;      // token stride for t%7
  int base;
  if (br == 0) {            // xy: (b,d,hb,wb), tok=(ih,iw)
    int b = lbid >> 9, r = lbid & 511;
    int d = r >> 6, hb = (r >> 3) & 7, wb = r & 7;
    base = ((b * 8 + d) * 56 + hb * 7) * 56 + wb * 7;
  } else if (br == 1) {     // ty: (b,hb,wcol), tok=(id,ih)
    int b = lbid / 448, r = lbid % 448;
    int hb = r / 56, wc = r % 56;
    base = (b * 448 + hb * 7) * 56 + wc;
  } else {                  // tx: (b,h,wb), tok=(id,iw)
    int b = lbid / 448, r = lbid % 448;
    int h = r >> 3, wb = r & 7;
    base = (b * 448 + h) * 56 + wb * 7;
  }
  const short* wqkvT  = wsT + br * 49152;
  const short* wprojT = wsT + 3 * 49152 + br * 16384;
  const float* bqkv  = (br == 0) ? bq0 : (br == 1) ? bq1 : bq2;
  const float* bproj = (br == 0) ? bp0 : (br == 1) ? bp1 : bp2;

  // ---- Phase 1: stage x window -> XS (RA), bf16, pad rows zeroed ----
  {
    int rg = tid >> 5;               // 2 rows per wave-instr
    int c4 = (tid & 31) << 2;        // col 0..124 step 4
    #pragma unroll
    for (int it = 0; it < 4; ++it) {
      int t = rg + it * 16;
      uint2v v2;
      if (t < NTOK) {
        int q = (unsigned)t / 7u, rm = t - q * 7;
        float4 xv = *(const float4*)(x + (((size_t)(base + q * S1 + rm * S2)) << 7) + c4);
        v2.x = pk2(xv.x, xv.y);
        v2.y = pk2(xv.z, xv.w);
      } else {
        v2.x = 0; v2.y = 0;
      }
      *(uint2v*)(&smem[RA + t * 256 + SWZ16(t, c4 * 2)]) = v2;
    }
  }
  __syncthreads();   // ---- bar 1 ----

  const int mt = w & 3, ng = w >> 2;       // wave's m-tile / n-half
  const int arow = mt * 16 + l15;

  // ---- Phase 2: QKV gemm [64 x 384], all heads at once ----
  floatx4 vacc[4];                          // V part held in regs across bar 2
  {
    #pragma unroll
    for (int p = 0; p < 2; ++p) {           // p=0: Q, p=1: K
      floatx4 acc[4];
      #pragma unroll
      for (int i = 0; i < 4; ++i) acc[i] = ZERO4;
      __builtin_amdgcn_s_setprio(1);
      #pragma unroll
      for (int kt = 0; kt < 4; ++kt) {
        short8v af = *(const short8v*)(&smem[RA + arow * 256 + SWZ16(arow, kt * 64 + l4 * 16)]);
        #pragma unroll
        for (int i = 0; i < 4; ++i) {
          int gcol = (p * 8 + ng * 4 + i) * 16 + l15;
          short8v bf = *(const short8v*)(wqkvT + (size_t)gcol * 128 + kt * 32 + l4 * 8);
          acc[i] = MFMA16(af, bf, acc[i]);
        }
      }
      __builtin_amdgcn_s_setprio(0);
      // scatter to Q (RB) / K (RC), +bias (+scale for Q via fmaf)
      int rbase = (p == 0) ? RB : RC;
      #pragma unroll
      for (int i = 0; i < 4; ++i) {
        int gcol = (p * 8 + ng * 4 + i) * 16 + l15;
        float bias = bqkv[gcol];
        float mul  = (p == 0) ? SCALE : 1.0f;
        float add  = (p == 0) ? bias * SCALE : bias;
        int c = gcol - p * 128;             // 0..127 channel
        #pragma unroll
        for (int r = 0; r < 4; ++r) {
          int row = mt * 16 + l4 * 4 + r;
          st16(&smem[rbase + row * 256 + SWZ16(row, c * 2)], fmaf(acc[i][r], mul, add));
        }
      }
    }
    // V part: keep accumulators, store only after bar 2 (VT aliases XS)
    #pragma unroll
    for (int i = 0; i < 4; ++i) vacc[i] = ZERO4;
    __builtin_amdgcn_s_setprio(1);
    #pragma unroll
    for (int kt = 0; kt < 4; ++kt) {
      short8v af = *(const short8v*)(&smem[RA + arow * 256 + SWZ16(arow, kt * 64 + l4 * 16)]);
      #pragma unroll
      for (int i = 0; i < 4; ++i) {
        int gcol = (16 + ng * 4 + i) * 16 + l15;
        short8v bf = *(const short8v*)(wqkvT + (size_t)gcol * 128 + kt * 32 + l4 * 8);
        vacc[i] = MFMA16(af, bf, vacc[i]);
      }
    }
    __builtin_amdgcn_s_setprio(0);
  }
  __syncthreads();   // ---- bar 2 : all XS reads done ----

  // ---- Phase 3a: scatter V^T into RA (row=c, col=kv) ----
  {
    #pragma unroll
    for (int i = 0; i < 4; ++i) {
      int gcol = (16 + ng * 4 + i) * 16 + l15;
      float bias = bqkv[gcol];
      int c = gcol - 256;                   // 0..127
      int kvb = mt * 16 + l4 * 4;
      uint2v pv;
      pv.x = pk2(vacc[i][0] + bias, vacc[i][1] + bias);
      pv.y = pk2(vacc[i][2] + bias, vacc[i][3] + bias);
      *(uint2v*)(&smem[RA + c * 128 + SWZ8(c, kvb * 2)]) = pv;
    }
  }

  // ---- Phase 3b: S^T = K Q^T in registers; per-lane softmax over kv ----
  // strip s = w, w+8 -> head h = s>>2, q-tile qt = s&3.  C[kv][q]:
  // kv = kvt*16 + l4*4 + r (in-lane over kvt,r + lane-group l4), q = qt*16+l15.
  floatx4 pT[2][4];                         // normalized P^T, kept across bar 3
  #pragma unroll
  for (int s2 = 0; s2 < 2; ++s2) {
    int s = w + s2 * 8;
    int h = s >> 2, qt = s & 3;
    int qrow = qt * 16 + l15;
    short8v bq = *(const short8v*)(&smem[RB + qrow * 256 + SWZ16(qrow, h * 64 + l4 * 16)]);
    floatx4 st[4];
    __builtin_amdgcn_s_setprio(1);
    #pragma unroll
    for (int kvt = 0; kvt < 4; ++kvt) {
      int krow = kvt * 16 + l15;
      short8v ak = *(const short8v*)(&smem[RC + krow * 256 + SWZ16(krow, h * 64 + l4 * 16)]);
      st[kvt] = MFMA16(ak, bq, ZERO4);      // swapped operands -> S^T tile
    }
    __builtin_amdgcn_s_setprio(0);
    // mask pad kv + in-lane max, 2-hop cross-group max
    float m0 = -1e30f;
    #pragma unroll
    for (int kvt = 0; kvt < 4; ++kvt) {
      #pragma unroll
      for (int r = 0; r < 4; ++r) {
        int kv = kvt * 16 + l4 * 4 + r;
        float sv = (kv < NTOK) ? st[kvt][r] : -1e30f;
        st[kvt][r] = sv;
        m0 = fmaxf(m0, sv);
      }
    }
    m0 = fmaxf(m0, __shfl_xor(m0, 16, 64));
    m0 = fmaxf(m0, __shfl_xor(m0, 32, 64));
    float sum = 0.f;
    #pragma unroll
    for (int kvt = 0; kvt < 4; ++kvt) {
      #pragma unroll
      for (int r = 0; r < 4; ++r) {
        float e = __expf(st[kvt][r] - m0);
        st[kvt][r] = e;
        sum += e;
      }
    }
    sum += __shfl_xor(sum, 16, 64);
    sum += __shfl_xor(sum, 32, 64);
    float rs = __builtin_amdgcn_rcpf(sum);
    #pragma unroll
    for (int kvt = 0; kvt < 4; ++kvt) {
      #pragma unroll
      for (int r = 0; r < 4; ++r) pT[s2][kvt][r] = st[kvt][r] * rs;
    }
  }
  __syncthreads();   // ---- bar 3 : all Q,K reads done ----

  // ---- Phase 4: scatter P^T (bf16) into RB/RC, packed b64 writes ----
  // P stored [64 q][128B kv] per head (same layout PV reads).
  #pragma unroll
  for (int s2 = 0; s2 < 2; ++s2) {
    int s = w + s2 * 8;
    int h = s >> 2, qt = s & 3;
    int pb = RB + h * 8192;
    int qrow = qt * 16 + l15;
    #pragma unroll
    for (int kvt = 0; kvt < 4; ++kvt) {
      uint2v pw;
      pw.x = pk2(pT[s2][kvt][0], pT[s2][kvt][1]);
      pw.y = pk2(pT[s2][kvt][2], pT[s2][kvt][3]);
      *(uint2v*)(&smem[pb + qrow * 128 + SWZ8(qrow, kvt * 32 + l4 * 8)]) = pw;
    }
  }
  __syncthreads();   // ---- bar 4 ----

  // ---- Phase 5: O = P V  (reads P in RB/RC, VT in RA) ----
  floatx4 oacc[4];
  {
    __builtin_amdgcn_s_setprio(1);
    #pragma unroll
    for (int i = 0; i < 4; ++i) {
      int nt = ng * 4 + i;                  // output c-tile 0..7
      int h = nt >> 1;
      int pb = RB + h * 8192;
      int prow = mt * 16 + l15;
      int vrow = nt * 16 + l15;             // VT row = channel
      floatx4 a = ZERO4;
      #pragma unroll
      for (int kt = 0; kt < 2; ++kt) {
        short8v ap = *(const short8v*)(&smem[pb + prow * 128 + SWZ8(prow, kt * 64 + l4 * 16)]);
        short8v bv = *(const short8v*)(&smem[RA + vrow * 128 + SWZ8(vrow, kt * 64 + l4 * 16)]);
        a = MFMA16(ap, bv, a);
      }
      oacc[i] = a;
    }
    __builtin_amdgcn_s_setprio(0);
  }
  __syncthreads();   // ---- bar 5 : all VT reads done ----

  // ---- Phase 6: scatter O (bf16) into RA ----
  #pragma unroll
  for (int i = 0; i < 4; ++i) {
    int c = (ng * 4 + i) * 16 + l15;
    #pragma unroll
    for (int r = 0; r < 4; ++r) {
      int row = mt * 16 + l4 * 4 + r;
      st16(&smem[RA + row * 256 + SWZ16(row, c * 2)], oacc[i][r]);
    }
  }
  __syncthreads();   // ---- bar 6 ----

  // ---- Phase 7: proj [64x128] = O[64x128] * Wp[128x128], atomicAdd out ----
  {
    floatx4 pacc[4];
    #pragma unroll
    for (int i = 0; i < 4; ++i) pacc[i] = ZERO4;
    __builtin_amdgcn_s_setprio(1);
    #pragma unroll
    for (int kt = 0; kt < 4; ++kt) {
      short8v ao = *(const short8v*)(&smem[RA + arow * 256 + SWZ16(arow, kt * 64 + l4 * 16)]);
      #pragma unroll
      for (int i = 0; i < 4; ++i) {
        int col = (ng * 4 + i) * 16 + l15;
        short8v bp = *(const short8v*)(wprojT + (size_t)col * 128 + kt * 32 + l4 * 8);
        pacc[i] = MFMA16(ao, bp, pacc[i]);
      }
    }
    __builtin_amdgcn_s_setprio(0);
    #pragma unroll
    for (int r = 0; r < 4; ++r) {
      int row = mt * 16 + l4 * 4 + r;
      if (row < NTOK) {
        int q = (unsigned)row / 7u, rm = row - q * 7;
        float* orow = out + (((size_t)(base + q * S1 + rm * S2)) << 7);
        #pragma unroll
        for (int i = 0; i < 4; ++i) {
          int col = (ng * 4 + i) * 16 + l15;
          atomicAdd(orow + col, pacc[i][r] + bproj[col]);
        }
      }
    }
  }
}

extern "C" void kernel_launch(void* const* d_in, const int* in_sizes, int n_in,
                              void* d_out, int out_size, void* d_ws, size_t ws_size,
                              hipStream_t stream) {
  const float* x         = (const float*)d_in[0];
  const float* qkv_w     = (const float*)d_in[1];
  const float* qkv_b     = (const float*)d_in[2];
  const float* qkv_th_w  = (const float*)d_in[3];
  const float* qkv_th_b  = (const float*)d_in[4];
  const float* qkv_tw_w  = (const float*)d_in[5];
  const float* qkv_tw_b  = (const float*)d_in[6];
  const float* proj_w    = (const float*)d_in[7];
  const float* proj_b    = (const float*)d_in[8];
  const float* proj_th_w = (const float*)d_in[9];
  const float* proj_th_b = (const float*)d_in[10];
  const float* proj_tw_w = (const float*)d_in[11];
  const float* proj_tw_b = (const float*)d_in[12];
  float* out = (float*)d_out;

  const int B = in_sizes[0] / (8 * 56 * 56 * 128);
  short* wsT = (short*)d_ws;

  // out = 0, then every branch accumulates atomically (order-free)
  (void)hipMemsetAsync(d_out, 0, (size_t)out_size * sizeof(float), stream);
  prep_weights<<<768, 256, 0, stream>>>(qkv_w, qkv_th_w, qkv_tw_w,
                                        proj_w, proj_th_w, proj_tw_w, wsT);

  const int nb0 = B * 512, nb1 = B * 448;
  wattn_all<<<nb0 + 2 * nb1, 512, 0, stream>>>(
      x, wsT, qkv_b, qkv_th_b, qkv_tw_b, proj_b, proj_th_b, proj_tw_b,
      out, nb0, nb1);
}